// Round 5
// baseline (280.362 us; speedup 1.0000x reference)
//
#include <hip/hip_runtime.h>
#include <cstdint>

#define M_ 8192
#define N_ 4096
#define K_ 4096

typedef unsigned short u16;
typedef __bf16 bf16x8 __attribute__((ext_vector_type(8)));
typedef float  f32x4  __attribute__((ext_vector_type(4)));
typedef u16    u16x8  __attribute__((ext_vector_type(8)));

__device__ __forceinline__ u16 f2bf(float f) {
  union { float f; uint32_t u; } v; v.f = f;
  uint32_t u = v.u;
  return (u16)((u + 0x7fffu + ((u >> 16) & 1u)) >> 16);  // RNE
}

__device__ __forceinline__ void async16(const u16* g, void* l) {
  __builtin_amdgcn_global_load_lds(
      (const __attribute__((address_space(1))) void*)g,
      (__attribute__((address_space(3))) void*)l, 16, 0, 0);
}

// ---------------- prologue: x (f32) -> bf16 ----------------
__global__ void cvt_x_kernel(const float* __restrict__ x, u16* __restrict__ xb) {
  const long total8 = (long)M_ * K_ / 8;
  long t = (long)blockIdx.x * blockDim.x + threadIdx.x;
  const long stride = (long)gridDim.x * blockDim.x;
  for (; t < total8; t += stride) {
    long e = t * 8;
    float4 a = *(const float4*)(x + e);
    float4 b = *(const float4*)(x + e + 4);
    u16x8 r;
    r[0] = f2bf(a.x); r[1] = f2bf(a.y); r[2] = f2bf(a.z); r[3] = f2bf(a.w);
    r[4] = f2bf(b.x); r[5] = f2bf(b.y); r[6] = f2bf(b.z); r[7] = f2bf(b.w);
    *(u16x8*)(xb + e) = r;
  }
}

// ---------------- prologue: W dequant -> bf16 ----------------
__global__ void build_w_kernel(const int* __restrict__ wi, const float* __restrict__ zp,
                               const float* __restrict__ dout, const float* __restrict__ din,
                               const int* __restrict__ eidx, u16* __restrict__ wb) {
  const int e = *eidx;
  const long total8 = (long)N_ * K_ / 8;
  long t = (long)blockIdx.x * blockDim.x + threadIdx.x;
  const long stride = (long)gridDim.x * blockDim.x;
  const float* dine = din + (long)e * K_;
  const float* doute = dout + (long)e * N_;
  for (; t < total8; t += stride) {
    long eo = t * 8;
    int o = (int)(eo >> 12);
    int c = (int)(eo & (K_ - 1));
    float z  = zp[o];
    float so = doute[o];
    int4 w0 = *(const int4*)(wi + eo);
    int4 w1 = *(const int4*)(wi + eo + 4);
    float4 d0 = *(const float4*)(dine + c);
    float4 d1 = *(const float4*)(dine + c + 4);
    u16x8 r;
    r[0] = f2bf(((float)w0.x - z) * so * d0.x);
    r[1] = f2bf(((float)w0.y - z) * so * d0.y);
    r[2] = f2bf(((float)w0.z - z) * so * d0.z);
    r[3] = f2bf(((float)w0.w - z) * so * d0.w);
    r[4] = f2bf(((float)w1.x - z) * so * d1.x);
    r[5] = f2bf(((float)w1.y - z) * so * d1.y);
    r[6] = f2bf(((float)w1.z - z) * so * d1.z);
    r[7] = f2bf(((float)w1.w - z) * so * d1.w);
    *(u16x8*)(wb + eo) = r;
  }
}

// ---- main GEMM: 256x256, BK=64, dbuf=2, K-split regions, read-ahead-1-phase ----
// Regions per buffer (16KB each, [256 rows][32 els]): Ak0, Ak1, Bk0, Bk1.
// Phases: P0=(k0,Y0) P1=(k0,Y1) P2=(k1,Y0) P3=(k1,Y1); 16 MFMA each;
// each phase reads the NEXT phase's 6 operand b128s (even LDS spread).
// Stages: P0:(t+1)Bk1  P1:(t+2)Ak0  P2:(t+2)Bk0  P3:(t+2)Ak1.
// Single gate VMC(4)@P1 guarantees (t+1){Ak0,Bk0,Ak1} + older landed.
// Swizzle: 16B slot ^= (row>>1)&3 within 64B rows (both sides, rule #21).
#define SBAR()   asm volatile("s_barrier" ::: "memory")
#define VMC_(n)  asm volatile("s_waitcnt vmcnt(" #n ")" ::: "memory")
#define VMC(n)   VMC_(n)
#define SCHED0() __builtin_amdgcn_sched_barrier(0)
#define RD(Lb, off) (*(const bf16x8*)((const u16*)(Lb) + (off)))

__global__ __launch_bounds__(512, 2) void gemm_kernel(const u16* __restrict__ A,
                                                      const u16* __restrict__ B,
                                                      const float* __restrict__ bias,
                                                      float* __restrict__ C) {
  extern __shared__ char ldsb[];
  char* LE = ldsb;
  char* LO = ldsb + 65536;
  const int tid  = threadIdx.x;
  const int lane = tid & 63;
  const int wave = tid >> 6;
  const int wm = wave >> 2;            // 0..1 -> 128-row half of A-tile
  const int wn = wave & 3;             // 0..3 -> 64-col quarter of B-tile
  const int fr = lane & 15, fq = lane >> 4;

  // XCD-aware swizzle (512 % 8 == 0 -> bijective)
  const int nwg = gridDim.x;
  const int wg  = blockIdx.x;
  const int swz = (wg & 7) * (nwg >> 3) + (wg >> 3);
  const int bm = swz >> 4;
  const int bn = swz & 15;
  const long brow = (long)bm * 256;
  const long bcol = (long)bn * 256;

  // staging: 2 x 16B per thread per region; linear LDS dest (tid*16, +8192),
  // inverse-swizzled global source slot (self-inverse XOR)
  const int gslot = (tid & 3) ^ ((tid >> 3) & 3);
  const int srow  = tid >> 2;
  const u16* pA0 = A + (brow + srow) * (long)K_ + gslot * 8;
  const u16* pA1 = A + (brow + srow + 128) * (long)K_ + gslot * 8;
  const u16* pB0 = B + (bcol + srow) * (long)K_ + gslot * 8;
  const u16* pB1 = B + (bcol + srow + 128) * (long)K_ + gslot * 8;
  const int Ld = tid * 16;

#define STAGE_(tile, reg, DB)                                                 \
  {                                                                           \
    const long _ko = (long)(tile) * 64 + ((reg) & 1) * 32;                    \
    char* _d = (DB) + (reg) * 16384 + Ld;                                     \
    if ((reg) < 2) { async16(pA0 + _ko, _d); async16(pA1 + _ko, _d + 8192); } \
    else           { async16(pB0 + _ko, _d); async16(pB1 + _ko, _d + 8192); } \
  }

  // read offsets (elements from buffer base); regions: Ak0=0 Ak1=8192 Bk0=16384 Bk1=24576
  const int slotE = (fq ^ ((fr >> 1) & 3)) * 8;
  const int baseA = (wm * 128 + fr) * 32 + slotE;           // + m*512 (+8192 for k1)
  const int baseB = 16384 + (wn * 64 + fr) * 32 + slotE;    // + n*512 (+8192 for k1)

  f32x4 acc[8][4] = {};
  bf16x8 aK0a[8], aK0b[8], aK1[8], bY0k0[2], bY1k0[2], bY0k1[2], bY1k1[2];

#define MFMA16(J0, J1, AARR, BARR)                                            \
  __builtin_amdgcn_s_setprio(1);                                              \
  _Pragma("unroll")                                                           \
  for (int m = 0; m < 8; ++m) {                                               \
    acc[m][J0] = __builtin_amdgcn_mfma_f32_16x16x32_bf16(AARR[m], BARR[0], acc[m][J0], 0, 0, 0); \
    acc[m][J1] = __builtin_amdgcn_mfma_f32_16x16x32_bf16(AARR[m], BARR[1], acc[m][J1], 0, 0, 0); \
  }                                                                           \
  __builtin_amdgcn_s_setprio(0);

#define PH0(T, BUF, OB, AIN, DOSTAGE)                                         \
  if (DOSTAGE) STAGE_((T) + 1, 3, OB);                                        \
  SBAR();                                                                     \
  bY1k0[0] = RD(BUF, baseB + 1024);                                           \
  bY1k0[1] = RD(BUF, baseB + 1536);                                           \
  aK1[0] = RD(BUF, baseA + 8192);                                             \
  aK1[1] = RD(BUF, baseA + 8192 + 512);                                       \
  aK1[2] = RD(BUF, baseA + 8192 + 1024);                                      \
  aK1[3] = RD(BUF, baseA + 8192 + 1536);                                      \
  SCHED0();                                                                   \
  MFMA16(0, 1, AIN, bY0k0)                                                    \
  SBAR();

#define PH1(T, BUF, AIN, DOSTAGE, VMN)                                        \
  if (DOSTAGE) STAGE_((T) + 2, 0, BUF);                                       \
  VMC(VMN);                                                                   \
  SBAR();                                                                     \
  aK1[4] = RD(BUF, baseA + 8192 + 2048);                                      \
  aK1[5] = RD(BUF, baseA + 8192 + 2560);                                      \
  aK1[6] = RD(BUF, baseA + 8192 + 3072);                                      \
  aK1[7] = RD(BUF, baseA + 8192 + 3584);                                      \
  bY0k1[0] = RD(BUF, baseB + 8192);                                           \
  bY0k1[1] = RD(BUF, baseB + 8192 + 512);                                     \
  SCHED0();                                                                   \
  MFMA16(2, 3, AIN, bY1k0)                                                    \
  SBAR();

#define PH2(T, BUF, NB, AOUT, DOSTAGE, RDNEXT)                                \
  if (DOSTAGE) STAGE_((T) + 2, 2, BUF);                                       \
  SBAR();                                                                     \
  bY1k1[0] = RD(BUF, baseB + 8192 + 1024);                                    \
  bY1k1[1] = RD(BUF, baseB + 8192 + 1536);                                    \
  if (RDNEXT) {                                                               \
    AOUT[0] = RD(NB, baseA);                                                  \
    AOUT[1] = RD(NB, baseA + 512);                                            \
    AOUT[2] = RD(NB, baseA + 1024);                                           \
    AOUT[3] = RD(NB, baseA + 1536);                                           \
  }                                                                           \
  SCHED0();                                                                   \
  MFMA16(0, 1, aK1, bY0k1)                                                    \
  SBAR();

#define PH3(T, BUF, NB, AOUT, DOSTAGE, RDNEXT)                                \
  if (DOSTAGE) STAGE_((T) + 2, 1, BUF);                                       \
  SBAR();                                                                     \
  if (RDNEXT) {                                                               \
    AOUT[4] = RD(NB, baseA + 2048);                                           \
    AOUT[5] = RD(NB, baseA + 2560);                                           \
    AOUT[6] = RD(NB, baseA + 3072);                                           \
    AOUT[7] = RD(NB, baseA + 3584);                                           \
    bY0k0[0] = RD(NB, baseB);                                                 \
    bY0k0[1] = RD(NB, baseB + 512);                                           \
  }                                                                           \
  SCHED0();                                                                   \
  MFMA16(2, 3, aK1, bY1k1)                                                    \
  SBAR();

  // prologue: stage t0 {Ak0,Bk0,Ak1,Bk1}, t1 {Ak0,Bk0,Ak1} (FIFO order matches loop)
  STAGE_(0, 0, LE); STAGE_(0, 2, LE); STAGE_(0, 1, LE); STAGE_(0, 3, LE);
  STAGE_(1, 0, LO); STAGE_(1, 2, LO); STAGE_(1, 1, LO);
  VMC(6);      // tile0 fully landed; (1){Ak0,Bk0,Ak1} may be outstanding
  SBAR();
#pragma unroll
  for (int m = 0; m < 8; ++m) aK0a[m] = RD(LE, baseA + m * 512);
  bY0k0[0] = RD(LE, baseB);
  bY0k0[1] = RD(LE, baseB + 512);

  for (int t = 0; t < 62; t += 2) {
    PH0(t, LE, LO, aK0a, 1)
    PH1(t, LE, aK0a, 1, 4)
    PH2(t, LE, LO, aK0b, 1, 1)
    PH3(t, LE, LO, aK0b, 1, 1)
    PH0(t + 1, LO, LE, aK0b, 1)
    PH1(t + 1, LO, aK0b, 1, 4)
    PH2(t + 1, LO, LE, aK0a, 1, 1)
    PH3(t + 1, LO, LE, aK0a, 1, 1)
  }
  // tile 62: only (63)Bk1 stage remains valid; tighter gate so (63)Ak1 lands
  PH0(62, LE, LO, aK0a, 1)
  PH1(62, LE, aK0a, 0, 2)
  PH2(62, LE, LO, aK0b, 0, 1)
  PH3(62, LE, LO, aK0b, 0, 1)
  // tile 63: no stages, no next reads; drain before Bk1(63)-dependent reads
  PH0(63, LO, LE, aK0b, 0)
  PH1(63, LO, aK0b, 0, 0)
  PH2(63, LO, LE, aK0a, 0, 0)
  PH3(63, LO, LE, aK0a, 0, 0)

#undef PH0
#undef PH1
#undef PH2
#undef PH3
#undef MFMA16
#undef STAGE_

  // epilogue: C/D layout col=lane&15, row=(lane>>4)*4+reg  [m89-verified]
  const int  ocol0 = (int)bcol + wn * 64;
  const long orow0 = brow + wm * 128;
  float bv[4];
#pragma unroll
  for (int n = 0; n < 4; ++n) bv[n] = bias[ocol0 + n * 16 + fr];
#pragma unroll
  for (int m = 0; m < 8; ++m) {
    long rb = orow0 + m * 16 + fq * 4;
#pragma unroll
    for (int n = 0; n < 4; ++n) {
      int col = ocol0 + n * 16 + fr;
#pragma unroll
      for (int j = 0; j < 4; ++j)
        C[(rb + j) * N_ + col] = acc[m][n][j] + bv[n];
    }
  }
}

// ---------------- fallback (only if ws too small) ----------------
__global__ void naive_kernel(const float* __restrict__ x, const int* __restrict__ wi,
                             const float* __restrict__ zp, const float* __restrict__ dout,
                             const float* __restrict__ din, const float* __restrict__ bias,
                             const int* __restrict__ eidx, float* __restrict__ y) {
  long t = (long)blockIdx.x * blockDim.x + threadIdx.x;
  if (t >= (long)M_ * N_) return;
  int  o = (int)(t & (N_ - 1));
  long r = t >> 12;
  int  e = *eidx;
  float z  = zp[o];
  float so = dout[(long)e * N_ + o];
  const float* xr = x + r * K_;
  const int*   wrow = wi + (long)o * K_;
  const float* dr = din + (long)e * K_;
  float s = 0.f;
  for (int k = 0; k < K_; ++k)
    s += xr[k] * (((float)wrow[k] - z) * dr[k]);
  y[t] = s * so + bias[o];
}

extern "C" void kernel_launch(void* const* d_in, const int* in_sizes, int n_in,
                              void* d_out, int out_size, void* d_ws, size_t ws_size,
                              hipStream_t stream) {
  const float* x    = (const float*)d_in[0];
  const int*   wi   = (const int*)d_in[1];
  const float* zp   = (const float*)d_in[2];
  const float* dout = (const float*)d_in[3];
  const float* din  = (const float*)d_in[4];
  const float* bias = (const float*)d_in[5];
  const int*   eidx = (const int*)d_in[6];
  float* y = (float*)d_out;

  const size_t need = (size_t)M_ * K_ * 2 + (size_t)N_ * K_ * 2;
  if (ws_size >= need) {
    u16* xb = (u16*)d_ws;
    u16* wb = xb + (size_t)M_ * K_;
    cvt_x_kernel<<<dim3(2048), dim3(256), 0, stream>>>(x, xb);
    build_w_kernel<<<dim3(2048), dim3(256), 0, stream>>>(wi, zp, dout, din, eidx, wb);
    (void)hipFuncSetAttribute((const void*)gemm_kernel,
                              hipFuncAttributeMaxDynamicSharedMemorySize, 131072);
    gemm_kernel<<<dim3((M_ / 256) * (N_ / 256)), dim3(512), 131072, stream>>>(xb, wb, bias, y);
  } else {
    long total = (long)M_ * N_;
    naive_kernel<<<dim3((unsigned)((total + 255) / 256)), dim3(256), 0, stream>>>(
        x, wi, zp, dout, din, bias, eidx, y);
  }
}

// Round 6
// 276.761 us; speedup vs baseline: 1.0130x; 1.0130x over previous
//
#include <hip/hip_runtime.h>
#include <cstdint>

#define M_ 8192
#define N_ 4096
#define K_ 4096

typedef unsigned short u16;
typedef __bf16 bf16x8 __attribute__((ext_vector_type(8)));
typedef float  f32x4  __attribute__((ext_vector_type(4)));
typedef u16    u16x8  __attribute__((ext_vector_type(8)));

__device__ __forceinline__ u16 f2bf(float f) {
  union { float f; uint32_t u; } v; v.f = f;
  uint32_t u = v.u;
  return (u16)((u + 0x7fffu + ((u >> 16) & 1u)) >> 16);  // RNE
}

__device__ __forceinline__ void async16(const u16* g, void* l) {
  __builtin_amdgcn_global_load_lds(
      (const __attribute__((address_space(1))) void*)g,
      (__attribute__((address_space(3))) void*)l, 16, 0, 0);
}

// ---------------- prologue: x (f32) -> bf16 ----------------
__global__ void cvt_x_kernel(const float* __restrict__ x, u16* __restrict__ xb) {
  const long total8 = (long)M_ * K_ / 8;
  long t = (long)blockIdx.x * blockDim.x + threadIdx.x;
  const long stride = (long)gridDim.x * blockDim.x;
  for (; t < total8; t += stride) {
    long e = t * 8;
    float4 a = *(const float4*)(x + e);
    float4 b = *(const float4*)(x + e + 4);
    u16x8 r;
    r[0] = f2bf(a.x); r[1] = f2bf(a.y); r[2] = f2bf(a.z); r[3] = f2bf(a.w);
    r[4] = f2bf(b.x); r[5] = f2bf(b.y); r[6] = f2bf(b.z); r[7] = f2bf(b.w);
    *(u16x8*)(xb + e) = r;
  }
}

// ---------------- prologue: W dequant -> bf16 ----------------
__global__ void build_w_kernel(const int* __restrict__ wi, const float* __restrict__ zp,
                               const float* __restrict__ dout, const float* __restrict__ din,
                               const int* __restrict__ eidx, u16* __restrict__ wb) {
  const int e = *eidx;
  const long total8 = (long)N_ * K_ / 8;
  long t = (long)blockIdx.x * blockDim.x + threadIdx.x;
  const long stride = (long)gridDim.x * blockDim.x;
  const float* dine = din + (long)e * K_;
  const float* doute = dout + (long)e * N_;
  for (; t < total8; t += stride) {
    long eo = t * 8;
    int o = (int)(eo >> 12);
    int c = (int)(eo & (K_ - 1));
    float z  = zp[o];
    float so = doute[o];
    int4 w0 = *(const int4*)(wi + eo);
    int4 w1 = *(const int4*)(wi + eo + 4);
    float4 d0 = *(const float4*)(dine + c);
    float4 d1 = *(const float4*)(dine + c + 4);
    u16x8 r;
    r[0] = f2bf(((float)w0.x - z) * so * d0.x);
    r[1] = f2bf(((float)w0.y - z) * so * d0.y);
    r[2] = f2bf(((float)w0.z - z) * so * d0.z);
    r[3] = f2bf(((float)w0.w - z) * so * d0.w);
    r[4] = f2bf(((float)w1.x - z) * so * d1.x);
    r[5] = f2bf(((float)w1.y - z) * so * d1.y);
    r[6] = f2bf(((float)w1.z - z) * so * d1.z);
    r[7] = f2bf(((float)w1.w - z) * so * d1.w);
    *(u16x8*)(wb + eo) = r;
  }
}

// ---- main GEMM: 256x256, BK=64, dbuf, 4 quadrant-phases, minimal fences ----
// Regions per 64KB buffer (16KB each): Alo(0) Ahi(16K) Blo(32K) Bhi(48K).
// "lo/hi" = per-wave quadrant halves: A rows with bit6==h; B rows with bit5==h.
// Phase reads (m201 12/4/8/0): P0:{Alo,Blo} P1:{Bhi} P2:{Ahi} P3:{}.
// Stages (for t+1): P0:Alo P1:Blo P2:Bhi P3:Ahi.
// Gates (only memory fences, FIFO-derived): VMC(4)@P0 covers (t)Bhi;
// VMC(4)@P1 covers (t)Ahi; VMC(4)@P3 covers (t+1){Alo,Blo}.
// Raw builtin barriers; un-clobbered lgkmcnt(0); no sched_barrier.
// Swizzle: 16B slot ^= (row&7) within 128B rows (both sides, rule #21).
#define VMC(n)   asm volatile("s_waitcnt vmcnt(" #n ")" ::: "memory")
#define LGKM0()  asm volatile("s_waitcnt lgkmcnt(0)")
#define BAR()    __builtin_amdgcn_s_barrier()
#define RD(p)    (*(const bf16x8*)(p))

__global__ __launch_bounds__(512, 2) void gemm_kernel(const u16* __restrict__ A,
                                                      const u16* __restrict__ B,
                                                      const float* __restrict__ bias,
                                                      float* __restrict__ C) {
  extern __shared__ char ldsb[];
  const int tid  = threadIdx.x;
  const int lane = tid & 63;
  const int wave = tid >> 6;
  const int wm = wave >> 2;            // 0..1 -> 128-row half of A-tile
  const int wn = wave & 3;             // 0..3 -> 64-col quarter of B-tile
  const int fr = lane & 15, fq = lane >> 4;

  // XCD-aware swizzle (512 % 8 == 0 -> bijective)
  const int nwg = gridDim.x;
  const int wg  = blockIdx.x;
  const int swz = (wg & 7) * (nwg >> 3) + (wg >> 3);
  const int bm = swz >> 4;
  const int bn = swz & 15;
  const long brow = (long)bm * 256;
  const long bcol = (long)bn * 256;

  // ---- staging geometry: 2 x 16B per thread per region ----
  const int slot_g = (tid & 7) ^ ((tid >> 3) & 7);   // inverse-swizzled src slot
  const int tr = tid >> 3;                           // 0..63
  const int b0row = (tr & 31) + ((tr >> 5) << 6);
  const u16* pA0 = A + (brow + tr) * (long)K_ + slot_g * 8;
  const u16* pB0 = B + (bcol + b0row) * (long)K_ + slot_g * 8;

  auto STAGE_A = [&](int tile, int h) {
    char* dst = ldsb + (tile & 1) * 65536 + h * 16384 + tid * 16;
    const long ko = (long)tile * 64 + (long)h * 64 * K_;
    async16(pA0 + ko, dst);
    async16(pA0 + ko + 128 * (long)K_, dst + 8192);
  };
  auto STAGE_B = [&](int tile, int h) {
    char* dst = ldsb + (tile & 1) * 65536 + 32768 + h * 16384 + tid * 16;
    const long ko = (long)tile * 64 + (long)h * 32 * K_;
    async16(pB0 + ko, dst);
    async16(pB0 + ko + 128 * (long)K_, dst + 8192);
  };

  // ---- ds_read offsets (elements from buffer base) ----
  const int swk0 = ((fq ^ (fr & 7)) << 3);
  const int swk1 = (((4 + fq) ^ (fr & 7)) << 3);
  int rA[4], rB[2];
#pragma unroll
  for (int m = 0; m < 4; ++m) rA[m] = (m * 16 + fr + wm * 64) * 64;
#pragma unroll
  for (int n = 0; n < 2; ++n) rB[n] = (n * 16 + fr + wn * 32) * 64;

  f32x4 acc[8][4] = {};
  bf16x8 aLo[8], aHi[8], bLo[4], bHi[4];   // [idx*2 + kk]

#define RD_ALO(buf)                                         \
  _Pragma("unroll")                                         \
  for (int m = 0; m < 4; ++m) {                             \
    aLo[m * 2]     = RD((buf) + rA[m] + swk0);              \
    aLo[m * 2 + 1] = RD((buf) + rA[m] + swk1);              \
  }
#define RD_AHI(buf)                                         \
  _Pragma("unroll")                                         \
  for (int m = 0; m < 4; ++m) {                             \
    aHi[m * 2]     = RD((buf) + 8192 + rA[m] + swk0);       \
    aHi[m * 2 + 1] = RD((buf) + 8192 + rA[m] + swk1);       \
  }
#define RD_BLO(buf)                                         \
  _Pragma("unroll")                                         \
  for (int n = 0; n < 2; ++n) {                             \
    bLo[n * 2]     = RD((buf) + 16384 + rB[n] + swk0);      \
    bLo[n * 2 + 1] = RD((buf) + 16384 + rB[n] + swk1);      \
  }
#define RD_BHI(buf)                                         \
  _Pragma("unroll")                                         \
  for (int n = 0; n < 2; ++n) {                             \
    bHi[n * 2]     = RD((buf) + 24576 + rB[n] + swk0);      \
    bHi[n * 2 + 1] = RD((buf) + 24576 + rB[n] + swk1);      \
  }
#define CLUST(MOFF, NOFF, AARR, BARR)                                           \
  __builtin_amdgcn_s_setprio(1);                                                \
  _Pragma("unroll")                                                             \
  for (int kk = 0; kk < 2; ++kk)                                                \
    _Pragma("unroll")                                                           \
    for (int m = 0; m < 4; ++m)                                                 \
      _Pragma("unroll")                                                         \
      for (int n = 0; n < 2; ++n)                                               \
        acc[m + MOFF][n + NOFF] = __builtin_amdgcn_mfma_f32_16x16x32_bf16(      \
            AARR[m * 2 + kk], BARR[n * 2 + kk], acc[m + MOFF][n + NOFF], 0, 0, 0); \
  __builtin_amdgcn_s_setprio(0);

  const int nk = K_ / 64;              // 64 K-tiles

  // prologue: stage tile 0 in FIFO order Alo,Blo,Bhi,Ahi
  STAGE_A(0, 0); STAGE_B(0, 0); STAGE_B(0, 1); STAGE_A(0, 1);
  VMC(4);                              // (0)Alo,(0)Blo landed
  BAR();

  for (int t = 0; t < nk - 1; ++t) {
    const u16* cur = (const u16*)(ldsb + (t & 1) * 65536);
    // P0: read {Alo,Blo}; stage (t+1)Alo; gate covers (t)Bhi
    RD_BLO(cur)
    RD_ALO(cur)
    STAGE_A(t + 1, 0);
    VMC(4);
    BAR(); LGKM0();
    CLUST(0, 0, aLo, bLo)
    BAR();
    // P1: read {Bhi}; stage (t+1)Blo; gate covers (t)Ahi
    RD_BHI(cur)
    STAGE_B(t + 1, 0);
    VMC(4);
    BAR(); LGKM0();
    CLUST(0, 2, aLo, bHi)
    BAR();
    // P2: read {Ahi}; stage (t+1)Bhi; no gate
    RD_AHI(cur)
    STAGE_B(t + 1, 1);
    BAR(); LGKM0();
    CLUST(4, 2, aHi, bHi)
    BAR();
    // P3: no reads; stage (t+1)Ahi; gate covers (t+1){Alo,Blo}
    STAGE_A(t + 1, 1);
    VMC(4);
    BAR();
    CLUST(4, 0, aHi, bLo)
    BAR();
  }

  // tail tile nk-1: no staging; tighter gates
  {
    const u16* cur = (const u16*)(ldsb + ((nk - 1) & 1) * 65536);
    RD_BLO(cur)
    RD_ALO(cur)
    VMC(2);                            // (63)Bhi landed
    BAR(); LGKM0();
    CLUST(0, 0, aLo, bLo)
    BAR();
    RD_BHI(cur)
    VMC(0);                            // (63)Ahi landed
    BAR(); LGKM0();
    CLUST(0, 2, aLo, bHi)
    BAR();
    RD_AHI(cur)
    BAR(); LGKM0();
    CLUST(4, 2, aHi, bHi)
    BAR();
    CLUST(4, 0, aHi, bLo)
  }

#undef RD_ALO
#undef RD_AHI
#undef RD_BLO
#undef RD_BHI
#undef CLUST

  // epilogue: C/D layout col=lane&15, row=(lane>>4)*4+reg  [m89-verified]
  const int  ocol0 = (int)bcol + wn * 64;
  const long orow0 = brow + wm * 128;
  float bv[4];
#pragma unroll
  for (int n = 0; n < 4; ++n) bv[n] = bias[ocol0 + n * 16 + fr];
#pragma unroll
  for (int m = 0; m < 8; ++m) {
    long rb = orow0 + m * 16 + fq * 4;
#pragma unroll
    for (int n = 0; n < 4; ++n) {
      int col = ocol0 + n * 16 + fr;
#pragma unroll
      for (int j = 0; j < 4; ++j)
        C[(rb + j) * N_ + col] = acc[m][n][j] + bv[n];
    }
  }
}

// ---------------- fallback (only if ws too small) ----------------
__global__ void naive_kernel(const float* __restrict__ x, const int* __restrict__ wi,
                             const float* __restrict__ zp, const float* __restrict__ dout,
                             const float* __restrict__ din, const float* __restrict__ bias,
                             const int* __restrict__ eidx, float* __restrict__ y) {
  long t = (long)blockIdx.x * blockDim.x + threadIdx.x;
  if (t >= (long)M_ * N_) return;
  int  o = (int)(t & (N_ - 1));
  long r = t >> 12;
  int  e = *eidx;
  float z  = zp[o];
  float so = dout[(long)e * N_ + o];
  const float* xr = x + r * K_;
  const int*   wrow = wi + (long)o * K_;
  const float* dr = din + (long)e * K_;
  float s = 0.f;
  for (int k = 0; k < K_; ++k)
    s += xr[k] * (((float)wrow[k] - z) * dr[k]);
  y[t] = s * so + bias[o];
}

extern "C" void kernel_launch(void* const* d_in, const int* in_sizes, int n_in,
                              void* d_out, int out_size, void* d_ws, size_t ws_size,
                              hipStream_t stream) {
  const float* x    = (const float*)d_in[0];
  const int*   wi   = (const int*)d_in[1];
  const float* zp   = (const float*)d_in[2];
  const float* dout = (const float*)d_in[3];
  const float* din  = (const float*)d_in[4];
  const float* bias = (const float*)d_in[5];
  const int*   eidx = (const int*)d_in[6];
  float* y = (float*)d_out;

  const size_t need = (size_t)M_ * K_ * 2 + (size_t)N_ * K_ * 2;
  if (ws_size >= need) {
    u16* xb = (u16*)d_ws;
    u16* wb = xb + (size_t)M_ * K_;
    cvt_x_kernel<<<dim3(2048), dim3(256), 0, stream>>>(x, xb);
    build_w_kernel<<<dim3(2048), dim3(256), 0, stream>>>(wi, zp, dout, din, eidx, wb);
    (void)hipFuncSetAttribute((const void*)gemm_kernel,
                              hipFuncAttributeMaxDynamicSharedMemorySize, 131072);
    gemm_kernel<<<dim3((M_ / 256) * (N_ / 256)), dim3(512), 131072, stream>>>(xb, wb, bias, y);
  } else {
    long total = (long)M_ * N_;
    naive_kernel<<<dim3((unsigned)((total + 255) / 256)), dim3(256), 0, stream>>>(
        x, wi, zp, dout, din, bias, eidx, y);
  }
}